// Round 3
// baseline (222.946 us; speedup 1.0000x reference)
//
#include <hip/hip_runtime.h>
#include <hip/hip_bf16.h>

#define B_  16
#define NQ_ 512
#define NK_ 1024
#define CQ_ 128
#define H_  8
#define D_  64
#define HD_ 512   // H*D

typedef __attribute__((ext_vector_type(8))) short short8;
typedef __attribute__((ext_vector_type(4))) float floatx4;

__device__ __forceinline__ short f2bf(float f) {
    union { float f; unsigned u; } x; x.f = f;
    unsigned r = (x.u + 0x7fffu + ((x.u >> 16) & 1u)) >> 16;  // RNE
    return (short)r;
}
__device__ __forceinline__ int f2bf_pk(float a, float b) {   // packed RNE (v_cvt_pk_bf16_f32)
    __hip_bfloat162 h = __float22bfloat162_rn(make_float2(a, b));
    int r; __builtin_memcpy(&r, &h, 4); return r;
}
__device__ __forceinline__ short8 pack8(float4 a, float4 b) {
    union { int4 i; short8 s; } u;
    u.i = make_int4(f2bf_pk(a.x, a.y), f2bf_pk(a.z, a.w),
                    f2bf_pk(b.x, b.y), f2bf_pk(b.z, b.w));
    return u.s;
}
__device__ __forceinline__ int2 packi2(floatx4 a) {
    return make_int2(f2bf_pk(a[0], a[1]), f2bf_pk(a[2], a[3]));
}
// async global->LDS, 16B per lane; LDS dest = uniform base + lane*16
__device__ __forceinline__ void async16(const short* g, short* l) {
    __builtin_amdgcn_global_load_lds(
        (const __attribute__((address_space(1))) void*)g,
        (__attribute__((address_space(3))) void*)l, 16, 0, 0);
}

// ---- Stage 0 (prep): W transposes + bqs + per-batch mask compaction ----
__global__ __launch_bounds__(256) void prep_kernel(
    const float* __restrict__ W0, const float* __restrict__ W1,
    const float* __restrict__ W2, short* __restrict__ T0,
    short* __restrict__ T1, short* __restrict__ T2,
    const float* __restrict__ bq, float* __restrict__ bqs, float qscale,
    const float* __restrict__ cmask, int* __restrict__ idx,
    float* __restrict__ cm2, int* __restrict__ npad)
{
    const int blk = blockIdx.x, t = threadIdx.x;
    if (blk == 48) {
        bqs[t]       = bq[t] * qscale;
        bqs[t + 256] = bq[t + 256] * qscale;
        return;
    }
    if (blk >= 49) {   // ---- mask compaction for batch b ----
        __shared__ int wsum[4];
        const int b = blk - 49;
        const int w = t >> 6, lane = t & 63;
        float4 m4 = *(const float4*)(cmask + b * NK_ + t * 4);
        const int m0 = m4.x > 0.5f, m1 = m4.y > 0.5f, m2 = m4.z > 0.5f, m3 = m4.w > 0.5f;
        const int s = m0 + m1 + m2 + m3;
        int v = s;
        #pragma unroll
        for (int off = 1; off < 64; off <<= 1) {
            int u = __shfl_up(v, off);
            if (lane >= off) v += u;
        }
        if (lane == 63) wsum[w] = v;
        __syncthreads();
        int pre = 0;
        #pragma unroll
        for (int i = 0; i < 4; ++i) if (i < w) pre += wsum[i];
        int pos = pre + v - s;                 // exclusive prefix for this thread
        const int base = b * NK_;
        if (m0) { idx[base + pos] = t * 4 + 0; cm2[base + pos] = 1.0f; ++pos; }
        if (m1) { idx[base + pos] = t * 4 + 1; cm2[base + pos] = 1.0f; ++pos; }
        if (m2) { idx[base + pos] = t * 4 + 2; cm2[base + pos] = 1.0f; ++pos; }
        if (m3) { idx[base + pos] = t * 4 + 3; cm2[base + pos] = 1.0f; ++pos; }
        const int total = wsum[0] + wsum[1] + wsum[2] + wsum[3];
        for (int j = total + t; j < NK_; j += 256) {   // pad slots
            idx[base + j] = 0; cm2[base + j] = 0.0f;
        }
        if (t == 0) npad[b] = (total + 127) & ~127;
        return;
    }
    // ---- W transpose ----
    __shared__ short tsh[32 * 132];    // [n][k], pad 132
    const int mat = blk >> 4, nb = blk & 15;          // n0 = nb*32
    const float* W = mat == 0 ? W0 : (mat == 1 ? W1 : W2);
    short* T = mat == 0 ? T0 : (mat == 1 ? T1 : T2);
    const float s = mat == 0 ? qscale : 1.0f;
    #pragma unroll
    for (int i = 0; i < 4; ++i) {
        const int i2 = i * 256 + t;                   // 0..1023
        const int k = i2 >> 3, c = (i2 & 7) * 4;
        float4 v = *(const float4*)(W + (size_t)k * HD_ + nb * 32 + c);
        tsh[(c + 0) * 132 + k] = f2bf(v.x * s);
        tsh[(c + 1) * 132 + k] = f2bf(v.y * s);
        tsh[(c + 2) * 132 + k] = f2bf(v.z * s);
        tsh[(c + 3) * 132 + k] = f2bf(v.w * s);
    }
    __syncthreads();
    #pragma unroll
    for (int j = 0; j < 2; ++j) {
        const int i2 = j * 256 + t;                   // 0..511
        const int n = i2 >> 4, seg = (i2 & 15) * 8;
        *(short8*)(T + (size_t)(nb * 32 + n) * CQ_ + seg) =
            *(const short8*)&tsh[n * 132 + seg];
    }
}

// ---- Fused producer->consumer: each block does one kvproj share, then
// one attn share. Per-(b, head-pair, K/V) ready flags (device-scope
// release/acquire) replace the kernel boundary: attention for a (b,h)
// starts as soon as its 16 producer blocks are done, overlapping with the
// remaining projections. Deadlock-free at any occupancy: the producer
// share runs unconditionally before any wait. Flags are monotonic
// (consumers test < 8), so rocprof replay without re-zeroing is safe.
__global__ __launch_bounds__(256, 4) void kvattn_kernel(
    const float* __restrict__ query, const float* __restrict__ key_,
    const short* __restrict__ wqt, const short* __restrict__ wkt,
    const short* __restrict__ wvt, const float* __restrict__ bk,
    const float* __restrict__ bv, const float* __restrict__ bqs,
    const int* __restrict__ idx, const float* __restrict__ cm2,
    const int* __restrict__ npad, short* __restrict__ ks,
    short* __restrict__ vt, unsigned* __restrict__ flags,
    float* __restrict__ out)
{
    __shared__ __align__(16) char smem[40960];   // union: csh 18KB | attn 40KB
    const int tid = threadIdx.x;
    const int w = tid >> 6, lane = tid & 63;
    const int l15 = lane & 15, quad = lane >> 4;

    // ================= producer: K/V projection share =================
    {
        int bx = blockIdx.x & 255;
        const int y = blockIdx.x >> 8;           // head pair 0..3
        const short* Wt; const float* bias; short* op; int transposed;
        if (bx < 128) { Wt = wkt; bias = bk; op = ks; transposed = 0; }
        else { bx -= 128; Wt = wvt; bias = bv; op = vt; transposed = 1; }

        const int mbase = bx * 128;
        const int b  = mbase >> 10;
        const int r0 = mbase & 1023;
        if (r0 < npad[b]) {                      // compacted tail: just flag
            short* csh = (short*)smem;           // k: [m][n] s72; v: [n][m] s136
            const int* ib = idx + b * NK_;

            short8 afr[2][4];
            #pragma unroll
            for (int mt = 0; mt < 2; ++mt) {
                const int krow = ib[r0 + w * 32 + mt * 16 + l15];
                const float* xrow = key_ + (size_t)(b * NK_ + krow) * CQ_;
                #pragma unroll
                for (int kt = 0; kt < 4; ++kt)
                    afr[mt][kt] = pack8(*(const float4*)(xrow + kt * 32 + quad * 8),
                                        *(const float4*)(xrow + kt * 32 + quad * 8 + 4));
            }

            #pragma unroll
            for (int hh = 0; hh < 2; ++hh) {
                const int h = y * 2 + hh;
                short8 bfr[4][4];
                #pragma unroll
                for (int nt = 0; nt < 4; ++nt) {
                    const short8* wrow = (const short8*)(Wt + (size_t)(h * 64 + nt * 16 + l15) * CQ_);
                    #pragma unroll
                    for (int kt = 0; kt < 4; ++kt) bfr[nt][kt] = wrow[kt * 4 + quad];
                }
                floatx4 acc[2][4];
                #pragma unroll
                for (int mt = 0; mt < 2; ++mt)
                    #pragma unroll
                    for (int nt = 0; nt < 4; ++nt) {
                        floatx4 a = {0.f, 0.f, 0.f, 0.f};
                        #pragma unroll
                        for (int kt = 0; kt < 4; ++kt)
                            a = __builtin_amdgcn_mfma_f32_16x16x32_bf16(afr[mt][kt], bfr[nt][kt], a, 0, 0, 0);
                        acc[mt][nt] = a;
                    }
                __syncthreads();   // previous head's csh reads done
                #pragma unroll
                for (int mt = 0; mt < 2; ++mt)
                    #pragma unroll
                    for (int nt = 0; nt < 4; ++nt) {
                        const float bvv = bias[h * 64 + nt * 16 + l15];
                        #pragma unroll
                        for (int i = 0; i < 4; ++i) {
                            const short sv = f2bf(acc[mt][nt][i] + bvv);
                            const int m = w * 32 + mt * 16 + quad * 4 + i;
                            const int n = nt * 16 + l15;
                            if (!transposed) csh[m * 72 + n]  = sv;
                            else             csh[n * 136 + m] = sv;
                        }
                    }
                __syncthreads();

                const size_t bh = (size_t)(b * H_ + h);
                if (!transposed) {
                    short* dst = op + (bh * NK_ + r0) * D_;      // contiguous region
                    #pragma unroll
                    for (int it = 0; it < 4; ++it) {
                        const int i2 = it * 256 + tid;           // 0..1023
                        const int row = i2 >> 3, c8 = (i2 & 7) * 8;
                        *(short8*)(dst + i2 * 8) = *(const short8*)&csh[row * 72 + c8];
                    }
                } else {
                    short* dst = op + bh * D_ * NK_ + r0;        // 64 rows, stride NK
                    #pragma unroll
                    for (int it = 0; it < 4; ++it) {
                        const int i2 = it * 256 + tid;
                        const int row = i2 >> 4, c8 = (i2 & 15) * 8;
                        *(short8*)(dst + (size_t)row * NK_ + c8) = *(const short8*)&csh[row * 136 + c8];
                    }
                }
            }
            __syncthreads();   // all waves' stores drained (vmcnt0) before flag
        }
        if (tid == 0) {
            __threadfence();   // release: K/V tile visible device-wide
            atomicAdd(&flags[(b * 4 + y) * 2 + transposed], 1u);
        }
    }

    // ================= consumer: flash attention share =================
    {
        short* const kbuf0 = (short*)smem;            // [2][64*64]  16KB
        short* const vbuf0 = (short*)smem + 8192;     // [2][64*64]  16KB
        short* const psh   = (short*)smem + 16384;    // [64*64]      8KB

        const int bx   = blockIdx.x;
        const int bh_i = bx & 127;            // bh%8 tracks dispatch%8 -> XCD locality
        const int qq   = bx >> 7;             // 0..7 (64 q-rows each)
        const int h    = bh_i & 7;
        const int b    = bh_i >> 3;

        const size_t bh = (size_t)bh_i;
        const short* kb_ = ks + bh * NK_ * D_;
        const short* vb  = vt + bh * D_ * NK_;
        const float* mk  = cm2 + (size_t)b * NK_;
        const int nc = npad[b] >> 6;          // compacted chunk count

        const int prow = w * 16 + l15;        // this lane's q-row within block

        // --- Q projection first (no K/V dependency): overlaps the wait ---
        short8 qa[2];
        {
            short8 waf[4][4];
            #pragma unroll
            for (int dt = 0; dt < 4; ++dt)
                #pragma unroll
                for (int kt = 0; kt < 4; ++kt)
                    waf[dt][kt] = *(const short8*)(wqt + (size_t)(h * 64 + dt * 16 + l15) * CQ_ + kt * 32 + quad * 8);
            const float* qrow = query + ((size_t)b * NQ_ + qq * 64 + prow) * CQ_;
            short8 bqf[4];
            #pragma unroll
            for (int kt = 0; kt < 4; ++kt)
                bqf[kt] = pack8(*(const float4*)(qrow + kt * 32 + quad * 8),
                                *(const float4*)(qrow + kt * 32 + quad * 8 + 4));
            #pragma unroll
            for (int dt = 0; dt < 4; ++dt) {
                float4 bi = *(const float4*)(bqs + h * 64 + dt * 16 + quad * 4);
                floatx4 a = {bi.x, bi.y, bi.z, bi.w};
                #pragma unroll
                for (int kt = 0; kt < 4; ++kt)
                    a = __builtin_amdgcn_mfma_f32_16x16x32_bf16(waf[dt][kt], bqf[kt], a, 0, 0, 0);
                const int c16 = (dt * 2 + (quad >> 1)) ^ (prow & 7);
                *(int2*)&psh[prow * 64 + c16 * 8 + (quad & 1) * 4] = packi2(a);
            }
            qa[0] = *(const short8*)&psh[prow * 64 + ((quad    ) ^ (prow & 7)) * 8];
            qa[1] = *(const short8*)&psh[prow * 64 + ((4 + quad) ^ (prow & 7)) * 8];
        }

        // --- wait for this (b, head-pair)'s K and V tiles (8 blocks each) ---
        if (tid == 0) {
            unsigned* fk = &flags[(b * 4 + (h >> 1)) * 2 + 0];
            unsigned* fv = &flags[(b * 4 + (h >> 1)) * 2 + 1];
            long long t0 = clock64();
            while (__hip_atomic_load(fk, __ATOMIC_RELAXED, __HIP_MEMORY_SCOPE_AGENT) < 8u ||
                   __hip_atomic_load(fv, __ATOMIC_RELAXED, __HIP_MEMORY_SCOPE_AGENT) < 8u) {
                __builtin_amdgcn_s_sleep(8);
                if (clock64() - t0 > (1ll << 30)) break;   // visible failure, not hang
            }
            __threadfence();   // acquire: no stale K/V lines
        }
        __syncthreads();

        // staging lane geometry: 8 lanes per row, 8 chunks of 16B per row
        const int srow8 = lane >> 3, sc = lane & 7;
        auto stage = [&](int kb0, short* kdst, short* vdst) {
            #pragma unroll
            for (int j = 0; j < 2; ++j) {
                const int row = w * 16 + j * 8 + srow8;
                const int cs = sc ^ (row & 7);
                async16(kb_ + (size_t)(kb0 + row) * D_ + cs * 8, &kdst[(w * 16 + j * 8) * 64]);
                async16(vb + (size_t)row * NK_ + kb0 + cs * 8, &vdst[(w * 16 + j * 8) * 64]);
            }
        };

        float l_lane = 0.f;
        floatx4 o_acc[4];
        #pragma unroll
        for (int dt = 0; dt < 4; ++dt) o_acc[dt] = (floatx4){0.f, 0.f, 0.f, 0.f};

        stage(0, kbuf0, vbuf0);
        __syncthreads();

        for (int t = 0; t < nc; ++t) {
            const int cur = t & 1;
            if (t + 1 < nc) stage((t + 1) * 64, kbuf0 + (cur ^ 1) * 4096, vbuf0 + (cur ^ 1) * 4096);
            const short* kb  = kbuf0 + cur * 4096;
            const short* vbl = vbuf0 + cur * 4096;
            const int kbase = t * 64;

            // K A-fragments (swizzled): A[m=key][k=d]
            short8 ka[4][2];
            #pragma unroll
            for (int nt = 0; nt < 4; ++nt) {
                const int row = nt * 16 + l15;
                ka[nt][0] = *(const short8*)&kb[row * 64 + ((quad    ) ^ (row & 7)) * 8];
                ka[nt][1] = *(const short8*)&kb[row * 64 + ((4 + quad) ^ (row & 7)) * 8];
            }
            // V fragments: lane map serves as A[m=d l15][k=key quad*8+j]
            short8 vf[2][4];
            #pragma unroll
            for (int dt = 0; dt < 4; ++dt) {
                const int row = dt * 16 + l15;
                vf[0][dt] = *(const short8*)&vbl[row * 64 + ((quad    ) ^ (row & 7)) * 8];
                vf[1][dt] = *(const short8*)&vbl[row * 64 + ((4 + quad) ^ (row & 7)) * 8];
            }
            // compacted mask (1 real / 0 pad) for this lane's keys
            float4 m4[4];
            #pragma unroll
            for (int nt = 0; nt < 4; ++nt)
                m4[nt] = *(const float4*)(mk + kbase + nt * 16 + quad * 4);

            // S^T = K·Q^T : D[m=key][n=query]
            floatx4 st[4];
            #pragma unroll
            for (int nt = 0; nt < 4; ++nt) {
                floatx4 a = {0.f, 0.f, 0.f, 0.f};
                a = __builtin_amdgcn_mfma_f32_16x16x32_bf16(ka[nt][1], qa[1], a, 0, 0, 0);
                a = __builtin_amdgcn_mfma_f32_16x16x32_bf16(ka[nt][0], qa[0], a, 0, 0, 0);
                st[nt] = a;
            }
            // p = mask * exp2(s); P -> psh (swizzled, wave-private rows)
            float psum = 0.f;
            #pragma unroll
            for (int nt = 0; nt < 4; ++nt) {
                float p0 = m4[nt].x * __builtin_amdgcn_exp2f(st[nt][0]);
                float p1 = m4[nt].y * __builtin_amdgcn_exp2f(st[nt][1]);
                float p2 = m4[nt].z * __builtin_amdgcn_exp2f(st[nt][2]);
                float p3 = m4[nt].w * __builtin_amdgcn_exp2f(st[nt][3]);
                psum += (p0 + p1) + (p2 + p3);
                int2 pk = make_int2(f2bf_pk(p0, p1), f2bf_pk(p2, p3));
                const int c16 = (2 * nt + (quad >> 1)) ^ (prow & 7);
                *(int2*)&psh[prow * 64 + c16 * 8 + (quad & 1) * 4] = pk;
            }
            l_lane += psum;
            // O^T += V^T·P^T (operand-swapped; same-wave psh write->read)
            #pragma unroll
            for (int kt = 0; kt < 2; ++kt) {
                short8 pa = *(const short8*)&psh[prow * 64 + ((kt * 4 + quad) ^ (prow & 7)) * 8];
                #pragma unroll
                for (int dt = 0; dt < 4; ++dt)
                    o_acc[dt] = __builtin_amdgcn_mfma_f32_16x16x32_bf16(vf[kt][dt], pa, o_acc[dt], 0, 0, 0);
            }
            __syncthreads();   // next chunk staged + all waves done with this buffer
        }

        // epilogue: O^T layout => q=l15, d=dt*16+quad*4+i; float4 stores
        {
            float ls = l_lane;
            ls += __shfl_xor(ls, 16);
            ls += __shfl_xor(ls, 32);
            const float linv = 1.0f / ls;
            const int qr = qq * 64 + prow;
            float* orow = out + ((size_t)b * NQ_ + qr) * HD_ + h * D_;
            #pragma unroll
            for (int dt = 0; dt < 4; ++dt) {
                float4 v = make_float4(o_acc[dt][0] * linv, o_acc[dt][1] * linv,
                                       o_acc[dt][2] * linv, o_acc[dt][3] * linv);
                *(float4*)(orow + dt * 16 + quad * 4) = v;
            }
        }
    }
}

extern "C" void kernel_launch(void* const* d_in, const int* in_sizes, int n_in,
                              void* d_out, int out_size, void* d_ws, size_t ws_size,
                              hipStream_t stream) {
    const float* query = (const float*)d_in[0];
    const float* key   = (const float*)d_in[1];
    const float* cmask = (const float*)d_in[2];
    const float* Wq    = (const float*)d_in[3];
    const float* bq    = (const float*)d_in[4];
    const float* Wk    = (const float*)d_in[5];
    const float* bk    = (const float*)d_in[6];
    const float* Wv    = (const float*)d_in[7];
    const float* bv    = (const float*)d_in[8];
    float* out = (float*)d_out;

    char* ws = (char*)d_ws;
    short* ks  = (short*)(ws);                           // 16 MB (B*H*NK*D bf16)
    short* vt  = (short*)(ws + (size_t)(16u << 20));     // 16 MB (B*H*D*NK bf16)
    char*  w32 = ws + (size_t)(32u << 20);
    short* wqt = (short*)(w32);                          // 128 KB each
    short* wkt = (short*)(w32 + 131072);
    short* wvt = (short*)(w32 + 131072 * 2);
    float* bqs = (float*)(w32 + 131072 * 3);             // 2 KB
    int*   idx = (int*)(w32 + 131072 * 3 + 4096);        // 64 KB (16*1024 int)
    float* cm2 = (float*)(w32 + 131072 * 3 + 4096 + 65536);  // 64 KB
    int*  npad = (int*)(w32 + 131072 * 3 + 4096 + 131072);   // 64 B
    unsigned* flags = (unsigned*)(w32 + 131072 * 3 + 4096 + 131072 + 1024); // 512 B

    hipMemsetAsync(flags, 0, 512, stream);   // reset ready-flags each replay

    const float qscale = 0.125f * 1.44269504f;    // 1/sqrt(64) * log2(e)
    prep_kernel<<<dim3(65), dim3(256), 0, stream>>>(
        Wq, Wk, Wv, wqt, wkt, wvt, bq, bqs, qscale, cmask, idx, cm2, npad);

    kvattn_kernel<<<dim3(1024), dim3(256), 0, stream>>>(
        query, key, wqt, wkt, wvt, bk, bv, bqs, idx, cm2, npad,
        ks, vt, flags, out);
}

// Round 4
// 167.679 us; speedup vs baseline: 1.3296x; 1.3296x over previous
//
#include <hip/hip_runtime.h>
#include <hip/hip_bf16.h>

#define B_  16
#define NQ_ 512
#define NK_ 1024
#define CQ_ 128
#define H_  8
#define D_  64
#define HD_ 512   // H*D

typedef __attribute__((ext_vector_type(8))) short short8;
typedef __attribute__((ext_vector_type(4))) float floatx4;

__device__ __forceinline__ short f2bf(float f) {
    union { float f; unsigned u; } x; x.f = f;
    unsigned r = (x.u + 0x7fffu + ((x.u >> 16) & 1u)) >> 16;  // RNE
    return (short)r;
}
__device__ __forceinline__ int f2bf_pk(float a, float b) {   // packed RNE (v_cvt_pk_bf16_f32)
    __hip_bfloat162 h = __float22bfloat162_rn(make_float2(a, b));
    int r; __builtin_memcpy(&r, &h, 4); return r;
}
__device__ __forceinline__ short8 pack8(float4 a, float4 b) {
    union { int4 i; short8 s; } u;
    u.i = make_int4(f2bf_pk(a.x, a.y), f2bf_pk(a.z, a.w),
                    f2bf_pk(b.x, b.y), f2bf_pk(b.z, b.w));
    return u.s;
}
__device__ __forceinline__ int2 packi2(floatx4 a) {
    return make_int2(f2bf_pk(a[0], a[1]), f2bf_pk(a[2], a[3]));
}

// ---- Stage 0 (prep): W transposes + bqs + per-batch mask compaction ----
__global__ __launch_bounds__(256) void prep_kernel(
    const float* __restrict__ W0, const float* __restrict__ W1,
    const float* __restrict__ W2, short* __restrict__ T0,
    short* __restrict__ T1, short* __restrict__ T2,
    const float* __restrict__ bq, float* __restrict__ bqs, float qscale,
    const float* __restrict__ cmask, int* __restrict__ idx,
    float* __restrict__ cm2, int* __restrict__ npad)
{
    const int blk = blockIdx.x, t = threadIdx.x;
    if (blk == 48) {
        bqs[t]       = bq[t] * qscale;
        bqs[t + 256] = bq[t + 256] * qscale;
        return;
    }
    if (blk >= 49) {   // ---- mask compaction for batch b ----
        __shared__ int wsum[4];
        const int b = blk - 49;
        const int w = t >> 6, lane = t & 63;
        float4 m4 = *(const float4*)(cmask + b * NK_ + t * 4);
        const int m0 = m4.x > 0.5f, m1 = m4.y > 0.5f, m2 = m4.z > 0.5f, m3 = m4.w > 0.5f;
        const int s = m0 + m1 + m2 + m3;
        int v = s;
        #pragma unroll
        for (int off = 1; off < 64; off <<= 1) {
            int u = __shfl_up(v, off);
            if (lane >= off) v += u;
        }
        if (lane == 63) wsum[w] = v;
        __syncthreads();
        int pre = 0;
        #pragma unroll
        for (int i = 0; i < 4; ++i) if (i < w) pre += wsum[i];
        int pos = pre + v - s;                 // exclusive prefix for this thread
        const int base = b * NK_;
        if (m0) { idx[base + pos] = t * 4 + 0; cm2[base + pos] = 1.0f; ++pos; }
        if (m1) { idx[base + pos] = t * 4 + 1; cm2[base + pos] = 1.0f; ++pos; }
        if (m2) { idx[base + pos] = t * 4 + 2; cm2[base + pos] = 1.0f; ++pos; }
        if (m3) { idx[base + pos] = t * 4 + 3; cm2[base + pos] = 1.0f; ++pos; }
        const int total = wsum[0] + wsum[1] + wsum[2] + wsum[3];
        for (int j = total + t; j < NK_; j += 256) {   // pad slots
            idx[base + j] = 0; cm2[base + j] = 0.0f;
        }
        if (t == 0) npad[b] = (total + 127) & ~127;
        return;
    }
    // ---- W transpose ----
    __shared__ short tsh[32 * 132];    // [n][k], pad 132
    const int mat = blk >> 4, nb = blk & 15;          // n0 = nb*32
    const float* W = mat == 0 ? W0 : (mat == 1 ? W1 : W2);
    short* T = mat == 0 ? T0 : (mat == 1 ? T1 : T2);
    const float s = mat == 0 ? qscale : 1.0f;
    #pragma unroll
    for (int i = 0; i < 4; ++i) {
        const int i2 = i * 256 + t;                   // 0..1023
        const int k = i2 >> 3, c = (i2 & 7) * 4;
        float4 v = *(const float4*)(W + (size_t)k * HD_ + nb * 32 + c);
        tsh[(c + 0) * 132 + k] = f2bf(v.x * s);
        tsh[(c + 1) * 132 + k] = f2bf(v.y * s);
        tsh[(c + 2) * 132 + k] = f2bf(v.z * s);
        tsh[(c + 3) * 132 + k] = f2bf(v.w * s);
    }
    __syncthreads();
    #pragma unroll
    for (int j = 0; j < 2; ++j) {
        const int i2 = j * 256 + t;                   // 0..511
        const int n = i2 >> 4, seg = (i2 & 15) * 8;
        *(short8*)(T + (size_t)(nb * 32 + n) * CQ_ + seg) =
            *(const short8*)&tsh[n * 132 + seg];
    }
}

// ---- Stage 1: streaming fused K/V-projection + flash attention ----
// grid 512 = (qq bits7-8, bh bits0-6), 256 threads (4 waves, 32 q-rows each).
// Per 64-key chunk: gather compacted key rows -> bf16 frags (register-
// prefetched one chunk ahead); these frags act BOTH as the K-proj A-operand
// and (identical lane map) the swapped V-proj B-operand. Projected K/V tiles
// go to swizzled LDS (one barrier), then the verified QK/softmax/PV body
// runs unchanged. No ks/vt global round-trip, no cross-block sync.
// K/V proj is recomputed per q-quarter (x4 redundancy, ~+7 GF — cheap).
__global__ __launch_bounds__(256, 2) void fused_attn(
    const float* __restrict__ query, const float* __restrict__ key_,
    const short* __restrict__ wqt, const short* __restrict__ wkt,
    const short* __restrict__ wvt, const float* __restrict__ bk,
    const float* __restrict__ bv, const float* __restrict__ bqs,
    const int* __restrict__ idx, const float* __restrict__ cm2,
    const int* __restrict__ npad, float* __restrict__ out)
{
    __shared__ __align__(16) short wk_lds[64 * 128];     // 16 KB, swizzled Wk^T slice
    __shared__ __align__(16) short kbuf[2][64 * 64];     // 16 KB
    __shared__ __align__(16) short vbuf[2][64 * 64];     // 16 KB
    __shared__ __align__(16) short psh[128 * 64];        // 16 KB, wave-private rows

    const int tid = threadIdx.x;
    const int w = tid >> 6, lane = tid & 63;
    const int l15 = lane & 15, quad = lane >> 4;

    const int bx   = blockIdx.x;
    const int bh_i = bx & 127;            // bh%8 tracks dispatch%8 -> XCD locality
    const int qq   = bx >> 7;             // 0..3 (128 q-rows each)
    const int h    = bh_i & 7;
    const int b    = bh_i >> 3;

    const float* mk = cm2 + (size_t)b * NK_;
    const int*   ib = idx + b * NK_;
    const int    nc = npad[b] >> 6;       // compacted chunk count

    // --- stage Wk^T head slice into LDS (16B-chunk XOR swizzle) ---
    {
        const short* wkg = wkt + (size_t)(h * 64) * CQ_;
        #pragma unroll
        for (int i = 0; i < 4; ++i) {
            const int i2 = i * 256 + tid;                 // 0..1023
            const int row = i2 >> 4, c = i2 & 15;
            *(short8*)&wk_lds[row * 128 + ((c ^ (row & 7)) * 8)] =
                *(const short8*)(wkg + (size_t)row * CQ_ + c * 8);
        }
    }
    // --- Wv^T head slice as resident A-fragments (invariant, 64 VGPR) ---
    short8 wvf[4][4];
    #pragma unroll
    for (int dt = 0; dt < 4; ++dt)
        #pragma unroll
        for (int kt = 0; kt < 4; ++kt)
            wvf[dt][kt] = *(const short8*)(wvt + (size_t)(h * 64 + dt * 16 + l15) * CQ_ + kt * 32 + quad * 8);
    // --- bias registers ---
    float bkf[4]; float4 bvf[4];
    #pragma unroll
    for (int nt = 0; nt < 4; ++nt) bkf[nt] = bk[h * 64 + nt * 16 + l15];
    #pragma unroll
    for (int dt = 0; dt < 4; ++dt) bvf[dt] = *(const float4*)(bv + h * 64 + dt * 16 + quad * 4);

    // --- Q projection (swapped: D[m=d][n=q]) via psh round-trip ---
    short8 qa[2][2];
    {
        short8 waf[4][4];
        #pragma unroll
        for (int dt = 0; dt < 4; ++dt)
            #pragma unroll
            for (int kt = 0; kt < 4; ++kt)
                waf[dt][kt] = *(const short8*)(wqt + (size_t)(h * 64 + dt * 16 + l15) * CQ_ + kt * 32 + quad * 8);
        const int qr0 = qq * 128 + w * 32;
        #pragma unroll
        for (int g = 0; g < 2; ++g) {
            const float* qrow = query + ((size_t)b * NQ_ + qr0 + g * 16 + l15) * CQ_;
            short8 bqf[4];
            #pragma unroll
            for (int kt = 0; kt < 4; ++kt)
                bqf[kt] = pack8(*(const float4*)(qrow + kt * 32 + quad * 8),
                                *(const float4*)(qrow + kt * 32 + quad * 8 + 4));
            const int prow = w * 32 + g * 16 + l15;
            #pragma unroll
            for (int dt = 0; dt < 4; ++dt) {
                float4 bi = *(const float4*)(bqs + h * 64 + dt * 16 + quad * 4);
                floatx4 a = {bi.x, bi.y, bi.z, bi.w};
                #pragma unroll
                for (int kt = 0; kt < 4; ++kt)
                    a = __builtin_amdgcn_mfma_f32_16x16x32_bf16(waf[dt][kt], bqf[kt], a, 0, 0, 0);
                const int c16 = (dt * 2 + (quad >> 1)) ^ (prow & 7);
                *(int2*)&psh[prow * 64 + c16 * 8 + (quad & 1) * 4] = packi2(a);
            }
            qa[g][0] = *(const short8*)&psh[prow * 64 + ((quad    ) ^ (prow & 7)) * 8];
            qa[g][1] = *(const short8*)&psh[prow * 64 + ((4 + quad) ^ (prow & 7)) * 8];
        }
    }
    __syncthreads();   // wk_lds staged (psh rows are wave-private)

    // --- gathered key-row prefetch (one chunk ahead, registers) ---
    float4 kr[8];
    auto gather = [&](int kbase) {
        const int krow = ib[kbase + w * 16 + l15];
        const float* xrow = key_ + (size_t)(b * NK_ + krow) * CQ_;
        #pragma unroll
        for (int kt = 0; kt < 4; ++kt) {
            kr[kt * 2]     = *(const float4*)(xrow + kt * 32 + quad * 8);
            kr[kt * 2 + 1] = *(const float4*)(xrow + kt * 32 + quad * 8 + 4);
        }
    };
    gather(0);

    float l_lane[2] = {0.f, 0.f};
    floatx4 o_acc[2][4];
    #pragma unroll
    for (int g = 0; g < 2; ++g)
        #pragma unroll
        for (int dt = 0; dt < 4; ++dt) o_acc[g][dt] = (floatx4){0.f, 0.f, 0.f, 0.f};

    for (int t = 0; t < nc; ++t) {
        const int cur = t & 1;
        short* kwr = kbuf[cur];
        short* vwr = vbuf[cur];

        // pack current chunk's A/B fragments; issue next chunk's gather
        short8 afr[4];
        #pragma unroll
        for (int kt = 0; kt < 4; ++kt) afr[kt] = pack8(kr[kt * 2], kr[kt * 2 + 1]);
        if (t + 1 < nc) gather((t + 1) * 64);

        // --- K-proj: D[m=key(16 of this wave)][n=d] ; afr is the A-operand ---
        #pragma unroll
        for (int nt = 0; nt < 4; ++nt) {
            floatx4 a = {0.f, 0.f, 0.f, 0.f};
            #pragma unroll
            for (int kt = 0; kt < 4; ++kt) {
                const int row = nt * 16 + l15;
                short8 bfr = *(const short8*)&wk_lds[row * 128 + (((kt * 4 + quad) ^ (row & 7)) * 8)];
                a = __builtin_amdgcn_mfma_f32_16x16x32_bf16(afr[kt], bfr, a, 0, 0, 0);
            }
            #pragma unroll
            for (int i = 0; i < 4; ++i) {          // key row = w*16+quad*4+i, d col = nt*16+l15
                const int krw = w * 16 + quad * 4 + i;
                const int cc = (nt * 2 + (l15 >> 3)) ^ (krw & 7);
                kwr[krw * 64 + cc * 8 + (l15 & 7)] = f2bf(a[i] + bkf[nt]);
            }
        }
        // --- V-proj (swapped): D[m=d][n=key] ; afr is the B-operand ---
        #pragma unroll
        for (int dt = 0; dt < 4; ++dt) {
            floatx4 a = {0.f, 0.f, 0.f, 0.f};
            #pragma unroll
            for (int kt = 0; kt < 4; ++kt)
                a = __builtin_amdgcn_mfma_f32_16x16x32_bf16(wvf[dt][kt], afr[kt], a, 0, 0, 0);
            const float* bvp = &bvf[dt].x;
            #pragma unroll
            for (int i = 0; i < 4; ++i) {          // d row = dt*16+quad*4+i, key col = w*16+l15
                const int dr = dt * 16 + quad * 4 + i;
                const int cc = (w * 2 + (l15 >> 3)) ^ (dr & 7);
                vwr[dr * 64 + cc * 8 + (l15 & 7)] = f2bf(a[i] + bvp[i]);
            }
        }
        __syncthreads();   // chunk's K/V tiles visible to all waves

        const short* kb  = kbuf[cur];
        const short* vbl = vbuf[cur];
        const int kbase = t * 64;

        // K A-fragments (swizzled): A[m=key][k=d]
        short8 ka[4][2];
        #pragma unroll
        for (int nt = 0; nt < 4; ++nt) {
            const int row = nt * 16 + l15;
            ka[nt][0] = *(const short8*)&kb[row * 64 + ((quad    ) ^ (row & 7)) * 8];
            ka[nt][1] = *(const short8*)&kb[row * 64 + ((4 + quad) ^ (row & 7)) * 8];
        }
        // V fragments: lane map serves as A[m=d l15][k=key quad*8+j]
        short8 vf[2][4];
        #pragma unroll
        for (int dt = 0; dt < 4; ++dt) {
            const int row = dt * 16 + l15;
            vf[0][dt] = *(const short8*)&vbl[row * 64 + ((quad    ) ^ (row & 7)) * 8];
            vf[1][dt] = *(const short8*)&vbl[row * 64 + ((4 + quad) ^ (row & 7)) * 8];
        }
        // compacted mask (1 real / 0 pad) for this lane's keys
        float4 m4[4];
        #pragma unroll
        for (int nt = 0; nt < 4; ++nt)
            m4[nt] = *(const float4*)(mk + kbase + nt * 16 + quad * 4);

        #pragma unroll
        for (int g = 0; g < 2; ++g) {
            // S^T = K·Q^T : D[m=key][n=query]
            floatx4 st[4];
            #pragma unroll
            for (int nt = 0; nt < 4; ++nt) {
                floatx4 a = {0.f, 0.f, 0.f, 0.f};
                a = __builtin_amdgcn_mfma_f32_16x16x32_bf16(ka[nt][1], qa[g][1], a, 0, 0, 0);
                a = __builtin_amdgcn_mfma_f32_16x16x32_bf16(ka[nt][0], qa[g][0], a, 0, 0, 0);
                st[nt] = a;
            }
            // p = mask * exp2(s); P -> psh (swizzled, wave-private rows)
            const int prow = w * 32 + g * 16 + l15;
            float psum = 0.f;
            #pragma unroll
            for (int nt = 0; nt < 4; ++nt) {
                float p0 = m4[nt].x * __builtin_amdgcn_exp2f(st[nt][0]);
                float p1 = m4[nt].y * __builtin_amdgcn_exp2f(st[nt][1]);
                float p2 = m4[nt].z * __builtin_amdgcn_exp2f(st[nt][2]);
                float p3 = m4[nt].w * __builtin_amdgcn_exp2f(st[nt][3]);
                psum += (p0 + p1) + (p2 + p3);
                int2 pk = make_int2(f2bf_pk(p0, p1), f2bf_pk(p2, p3));
                const int c16 = (2 * nt + (quad >> 1)) ^ (prow & 7);
                *(int2*)&psh[prow * 64 + c16 * 8 + (quad & 1) * 4] = pk;
            }
            l_lane[g] += psum;
            // O^T += V^T·P^T (operand-swapped; same-wave psh write->read)
            #pragma unroll
            for (int kt = 0; kt < 2; ++kt) {
                short8 pa = *(const short8*)&psh[prow * 64 + ((kt * 4 + quad) ^ (prow & 7)) * 8];
                #pragma unroll
                for (int dt = 0; dt < 4; ++dt)
                    o_acc[g][dt] = __builtin_amdgcn_mfma_f32_16x16x32_bf16(vf[kt][dt], pa, o_acc[g][dt], 0, 0, 0);
            }
        }
        // no trailing barrier: next iteration writes the other buffer; the
        // single barrier per chunk orders writes@t+2 after all reads@t.
    }

    // epilogue: O^T layout => q=l15, d=dt*16+quad*4+i; float4 stores
    #pragma unroll
    for (int g = 0; g < 2; ++g) {
        float ls = l_lane[g];
        ls += __shfl_xor(ls, 16);
        ls += __shfl_xor(ls, 32);
        const float linv = 1.0f / ls;
        const int qr = qq * 128 + w * 32 + g * 16 + l15;
        float* orow = out + ((size_t)b * NQ_ + qr) * HD_ + h * D_;
        #pragma unroll
        for (int dt = 0; dt < 4; ++dt) {
            float4 v = make_float4(o_acc[g][dt][0] * linv, o_acc[g][dt][1] * linv,
                                   o_acc[g][dt][2] * linv, o_acc[g][dt][3] * linv);
            *(float4*)(orow + dt * 16 + quad * 4) = v;
        }
    }
}

extern "C" void kernel_launch(void* const* d_in, const int* in_sizes, int n_in,
                              void* d_out, int out_size, void* d_ws, size_t ws_size,
                              hipStream_t stream) {
    const float* query = (const float*)d_in[0];
    const float* key   = (const float*)d_in[1];
    const float* cmask = (const float*)d_in[2];
    const float* Wq    = (const float*)d_in[3];
    const float* bq    = (const float*)d_in[4];
    const float* Wk    = (const float*)d_in[5];
    const float* bk    = (const float*)d_in[6];
    const float* Wv    = (const float*)d_in[7];
    const float* bv    = (const float*)d_in[8];
    float* out = (float*)d_out;

    char* ws = (char*)d_ws;
    short* wqt = (short*)(ws);                           // 128 KB each
    short* wkt = (short*)(ws + 131072);
    short* wvt = (short*)(ws + 131072 * 2);
    float* bqs = (float*)(ws + 131072 * 3);              // 2 KB
    int*   idx = (int*)(ws + 131072 * 3 + 4096);         // 64 KB (16*1024 int)
    float* cm2 = (float*)(ws + 131072 * 3 + 4096 + 65536);   // 64 KB
    int*  npad = (int*)(ws + 131072 * 3 + 4096 + 131072);    // 64 B

    const float qscale = 0.125f * 1.44269504f;    // 1/sqrt(64) * log2(e)
    prep_kernel<<<dim3(65), dim3(256), 0, stream>>>(
        Wq, Wk, Wv, wqt, wkt, wvt, bq, bqs, qscale, cmask, idx, cm2, npad);

    fused_attn<<<dim3(512), dim3(256), 0, stream>>>(
        query, key, wqt, wkt, wvt, bk, bv, bqs, idx, cm2, npad, out);
}

// Round 5
// 157.097 us; speedup vs baseline: 1.4192x; 1.0674x over previous
//
#include <hip/hip_runtime.h>
#include <hip/hip_bf16.h>

#define B_  16
#define NQ_ 512
#define NK_ 1024
#define CQ_ 128
#define H_  8
#define D_  64
#define HD_ 512   // H*D

typedef __attribute__((ext_vector_type(8))) short short8;
typedef __attribute__((ext_vector_type(4))) float floatx4;

__device__ __forceinline__ short f2bf(float f) {
    union { float f; unsigned u; } x; x.f = f;
    unsigned r = (x.u + 0x7fffu + ((x.u >> 16) & 1u)) >> 16;  // RNE
    return (short)r;
}
__device__ __forceinline__ int f2bf_pk(float a, float b) {   // packed RNE (v_cvt_pk_bf16_f32)
    __hip_bfloat162 h = __float22bfloat162_rn(make_float2(a, b));
    int r; __builtin_memcpy(&r, &h, 4); return r;
}
__device__ __forceinline__ short8 pack8(float4 a, float4 b) {
    union { int4 i; short8 s; } u;
    u.i = make_int4(f2bf_pk(a.x, a.y), f2bf_pk(a.z, a.w),
                    f2bf_pk(b.x, b.y), f2bf_pk(b.z, b.w));
    return u.s;
}
__device__ __forceinline__ int2 packi2(floatx4 a) {
    return make_int2(f2bf_pk(a[0], a[1]), f2bf_pk(a[2], a[3]));
}

// ---- Stage 0 (prep): W transposes + bqs + per-batch mask compaction ----
__global__ __launch_bounds__(256) void prep_kernel(
    const float* __restrict__ W0, const float* __restrict__ W1,
    const float* __restrict__ W2, short* __restrict__ T0,
    short* __restrict__ T1, short* __restrict__ T2,
    const float* __restrict__ bq, float* __restrict__ bqs, float qscale,
    const float* __restrict__ cmask, int* __restrict__ idx,
    float* __restrict__ cm2, int* __restrict__ npad)
{
    const int blk = blockIdx.x, t = threadIdx.x;
    if (blk == 48) {
        bqs[t]       = bq[t] * qscale;
        bqs[t + 256] = bq[t + 256] * qscale;
        return;
    }
    if (blk >= 49) {   // ---- mask compaction for batch b ----
        __shared__ int wsum[4];
        const int b = blk - 49;
        const int w = t >> 6, lane = t & 63;
        float4 m4 = *(const float4*)(cmask + b * NK_ + t * 4);
        const int m0 = m4.x > 0.5f, m1 = m4.y > 0.5f, m2 = m4.z > 0.5f, m3 = m4.w > 0.5f;
        const int s = m0 + m1 + m2 + m3;
        int v = s;
        #pragma unroll
        for (int off = 1; off < 64; off <<= 1) {
            int u = __shfl_up(v, off);
            if (lane >= off) v += u;
        }
        if (lane == 63) wsum[w] = v;
        __syncthreads();
        int pre = 0;
        #pragma unroll
        for (int i = 0; i < 4; ++i) if (i < w) pre += wsum[i];
        int pos = pre + v - s;                 // exclusive prefix for this thread
        const int base = b * NK_;
        if (m0) { idx[base + pos] = t * 4 + 0; cm2[base + pos] = 1.0f; ++pos; }
        if (m1) { idx[base + pos] = t * 4 + 1; cm2[base + pos] = 1.0f; ++pos; }
        if (m2) { idx[base + pos] = t * 4 + 2; cm2[base + pos] = 1.0f; ++pos; }
        if (m3) { idx[base + pos] = t * 4 + 3; cm2[base + pos] = 1.0f; ++pos; }
        const int total = wsum[0] + wsum[1] + wsum[2] + wsum[3];
        for (int j = total + t; j < NK_; j += 256) {   // pad slots
            idx[base + j] = 0; cm2[base + j] = 0.0f;
        }
        if (t == 0) npad[b] = (total + 127) & ~127;
        return;
    }
    // ---- W transpose ----
    __shared__ short tsh[32 * 132];    // [n][k], pad 132
    const int mat = blk >> 4, nb = blk & 15;          // n0 = nb*32
    const float* W = mat == 0 ? W0 : (mat == 1 ? W1 : W2);
    short* T = mat == 0 ? T0 : (mat == 1 ? T1 : T2);
    const float s = mat == 0 ? qscale : 1.0f;
    #pragma unroll
    for (int i = 0; i < 4; ++i) {
        const int i2 = i * 256 + t;                   // 0..1023
        const int k = i2 >> 3, c = (i2 & 7) * 4;
        float4 v = *(const float4*)(W + (size_t)k * HD_ + nb * 32 + c);
        tsh[(c + 0) * 132 + k] = f2bf(v.x * s);
        tsh[(c + 1) * 132 + k] = f2bf(v.y * s);
        tsh[(c + 2) * 132 + k] = f2bf(v.z * s);
        tsh[(c + 3) * 132 + k] = f2bf(v.w * s);
    }
    __syncthreads();
    #pragma unroll
    for (int j = 0; j < 2; ++j) {
        const int i2 = j * 256 + t;                   // 0..511
        const int n = i2 >> 4, seg = (i2 & 15) * 8;
        *(short8*)(T + (size_t)(nb * 32 + n) * CQ_ + seg) =
            *(const short8*)&tsh[n * 132 + seg];
    }
}

// ---- Stage 1: streaming fused K/V-projection + flash attention ----
// grid 512 = ((qq*8+h)*16 + b), 256 threads (4 waves, 32 q-rows each).
// bx mod 8 == b mod 8 (16 = 0 mod 8), so each XCD hosts exactly 2 batches
// (all heads, all q-quarters): keys (2x512KB) + queries (2x256KB) + W^T
// (768KB) ~ 2.3MB < 4MB L2 -> the x4-redundant key gather is L2-resident
// after first touch (R4's h-per-XCD mapping thrashed L2: FETCH 78MB).
// Per 64-key chunk: gather compacted key rows -> bf16 frags (register-
// prefetched one chunk ahead); frags act BOTH as K-proj A-operand and
// (identical lane map) swapped V-proj B-operand. Projected K/V tiles go
// to swizzled LDS (one barrier/chunk), then the verified QK/softmax/PV
// body runs unchanged. No global K/V round-trip, no cross-block sync.
__global__ __launch_bounds__(256, 2) void fused_attn(
    const float* __restrict__ query, const float* __restrict__ key_,
    const short* __restrict__ wqt, const short* __restrict__ wkt,
    const short* __restrict__ wvt, const float* __restrict__ bk,
    const float* __restrict__ bv, const float* __restrict__ bqs,
    const int* __restrict__ idx, const float* __restrict__ cm2,
    const int* __restrict__ npad, float* __restrict__ out)
{
    __shared__ __align__(16) short wk_lds[64 * 128];     // 16 KB, swizzled Wk^T slice
    __shared__ __align__(16) short kbuf[2][64 * 64];     // 16 KB
    __shared__ __align__(16) short vbuf[2][64 * 64];     // 16 KB
    __shared__ __align__(16) short psh[128 * 64];        // 16 KB, wave-private rows

    const int tid = threadIdx.x;
    const int w = tid >> 6, lane = tid & 63;
    const int l15 = lane & 15, quad = lane >> 4;

    const int bx = blockIdx.x;
    const int b  = bx & 15;               // bx%8 == b%8 -> batch-local XCD
    const int qh = bx >> 4;
    const int h  = qh & 7;
    const int qq = qh >> 3;               // 0..3 (128 q-rows each)

    const float* mk = cm2 + (size_t)b * NK_;
    const int*   ib = idx + b * NK_;
    const int    nc = npad[b] >> 6;       // compacted chunk count

    // --- stage Wk^T head slice into LDS (16B-chunk XOR swizzle) ---
    {
        const short* wkg = wkt + (size_t)(h * 64) * CQ_;
        #pragma unroll
        for (int i = 0; i < 4; ++i) {
            const int i2 = i * 256 + tid;                 // 0..1023
            const int row = i2 >> 4, c = i2 & 15;
            *(short8*)&wk_lds[row * 128 + ((c ^ (row & 7)) * 8)] =
                *(const short8*)(wkg + (size_t)row * CQ_ + c * 8);
        }
    }
    // --- Wv^T head slice as resident A-fragments (invariant, 64 VGPR) ---
    short8 wvf[4][4];
    #pragma unroll
    for (int dt = 0; dt < 4; ++dt)
        #pragma unroll
        for (int kt = 0; kt < 4; ++kt)
            wvf[dt][kt] = *(const short8*)(wvt + (size_t)(h * 64 + dt * 16 + l15) * CQ_ + kt * 32 + quad * 8);
    // --- bias registers ---
    float bkf[4]; float4 bvf[4];
    #pragma unroll
    for (int nt = 0; nt < 4; ++nt) bkf[nt] = bk[h * 64 + nt * 16 + l15];
    #pragma unroll
    for (int dt = 0; dt < 4; ++dt) bvf[dt] = *(const float4*)(bv + h * 64 + dt * 16 + quad * 4);

    // --- Q projection (swapped: D[m=d][n=q]) via psh round-trip ---
    short8 qa[2][2];
    {
        short8 waf[4][4];
        #pragma unroll
        for (int dt = 0; dt < 4; ++dt)
            #pragma unroll
            for (int kt = 0; kt < 4; ++kt)
                waf[dt][kt] = *(const short8*)(wqt + (size_t)(h * 64 + dt * 16 + l15) * CQ_ + kt * 32 + quad * 8);
        const int qr0 = qq * 128 + w * 32;
        #pragma unroll
        for (int g = 0; g < 2; ++g) {
            const float* qrow = query + ((size_t)b * NQ_ + qr0 + g * 16 + l15) * CQ_;
            short8 bqf[4];
            #pragma unroll
            for (int kt = 0; kt < 4; ++kt)
                bqf[kt] = pack8(*(const float4*)(qrow + kt * 32 + quad * 8),
                                *(const float4*)(qrow + kt * 32 + quad * 8 + 4));
            const int prow = w * 32 + g * 16 + l15;
            #pragma unroll
            for (int dt = 0; dt < 4; ++dt) {
                float4 bi = *(const float4*)(bqs + h * 64 + dt * 16 + quad * 4);
                floatx4 a = {bi.x, bi.y, bi.z, bi.w};
                #pragma unroll
                for (int kt = 0; kt < 4; ++kt)
                    a = __builtin_amdgcn_mfma_f32_16x16x32_bf16(waf[dt][kt], bqf[kt], a, 0, 0, 0);
                const int c16 = (dt * 2 + (quad >> 1)) ^ (prow & 7);
                *(int2*)&psh[prow * 64 + c16 * 8 + (quad & 1) * 4] = packi2(a);
            }
            qa[g][0] = *(const short8*)&psh[prow * 64 + ((quad    ) ^ (prow & 7)) * 8];
            qa[g][1] = *(const short8*)&psh[prow * 64 + ((4 + quad) ^ (prow & 7)) * 8];
        }
    }
    __syncthreads();   // wk_lds staged (psh rows are wave-private)

    // --- gathered key-row prefetch (one chunk ahead, registers) ---
    float4 kr[8];
    auto gather = [&](int kbase) {
        const int krow = ib[kbase + w * 16 + l15];
        const float* xrow = key_ + (size_t)(b * NK_ + krow) * CQ_;
        #pragma unroll
        for (int kt = 0; kt < 4; ++kt) {
            kr[kt * 2]     = *(const float4*)(xrow + kt * 32 + quad * 8);
            kr[kt * 2 + 1] = *(const float4*)(xrow + kt * 32 + quad * 8 + 4);
        }
    };
    gather(0);

    float l_lane[2] = {0.f, 0.f};
    floatx4 o_acc[2][4];
    #pragma unroll
    for (int g = 0; g < 2; ++g)
        #pragma unroll
        for (int dt = 0; dt < 4; ++dt) o_acc[g][dt] = (floatx4){0.f, 0.f, 0.f, 0.f};

    for (int t = 0; t < nc; ++t) {
        const int cur = t & 1;
        short* kwr = kbuf[cur];
        short* vwr = vbuf[cur];

        // pack current chunk's A/B fragments; issue next chunk's gather
        short8 afr[4];
        #pragma unroll
        for (int kt = 0; kt < 4; ++kt) afr[kt] = pack8(kr[kt * 2], kr[kt * 2 + 1]);
        if (t + 1 < nc) gather((t + 1) * 64);

        // --- K-proj: D[m=key(16 of this wave)][n=d] ; afr is the A-operand ---
        #pragma unroll
        for (int nt = 0; nt < 4; ++nt) {
            floatx4 a = {0.f, 0.f, 0.f, 0.f};
            #pragma unroll
            for (int kt = 0; kt < 4; ++kt) {
                const int row = nt * 16 + l15;
                short8 bfr = *(const short8*)&wk_lds[row * 128 + (((kt * 4 + quad) ^ (row & 7)) * 8)];
                a = __builtin_amdgcn_mfma_f32_16x16x32_bf16(afr[kt], bfr, a, 0, 0, 0);
            }
            #pragma unroll
            for (int i = 0; i < 4; ++i) {          // key row = w*16+quad*4+i, d col = nt*16+l15
                const int krw = w * 16 + quad * 4 + i;
                const int cc = (nt * 2 + (l15 >> 3)) ^ (krw & 7);
                kwr[krw * 64 + cc * 8 + (l15 & 7)] = f2bf(a[i] + bkf[nt]);
            }
        }
        // --- V-proj (swapped): D[m=d][n=key] ; afr is the B-operand ---
        #pragma unroll
        for (int dt = 0; dt < 4; ++dt) {
            floatx4 a = {0.f, 0.f, 0.f, 0.f};
            #pragma unroll
            for (int kt = 0; kt < 4; ++kt)
                a = __builtin_amdgcn_mfma_f32_16x16x32_bf16(wvf[dt][kt], afr[kt], a, 0, 0, 0);
            const float* bvp = &bvf[dt].x;
            #pragma unroll
            for (int i = 0; i < 4; ++i) {          // d row = dt*16+quad*4+i, key col = w*16+l15
                const int dr = dt * 16 + quad * 4 + i;
                const int cc = (w * 2 + (l15 >> 3)) ^ (dr & 7);
                vwr[dr * 64 + cc * 8 + (l15 & 7)] = f2bf(a[i] + bvp[i]);
            }
        }
        __syncthreads();   // chunk's K/V tiles visible to all waves

        const short* kb  = kbuf[cur];
        const short* vbl = vbuf[cur];
        const int kbase = t * 64;

        // K A-fragments (swizzled): A[m=key][k=d]
        short8 ka[4][2];
        #pragma unroll
        for (int nt = 0; nt < 4; ++nt) {
            const int row = nt * 16 + l15;
            ka[nt][0] = *(const short8*)&kb[row * 64 + ((quad    ) ^ (row & 7)) * 8];
            ka[nt][1] = *(const short8*)&kb[row * 64 + ((4 + quad) ^ (row & 7)) * 8];
        }
        // V fragments: lane map serves as A[m=d l15][k=key quad*8+j]
        short8 vf[2][4];
        #pragma unroll
        for (int dt = 0; dt < 4; ++dt) {
            const int row = dt * 16 + l15;
            vf[0][dt] = *(const short8*)&vbl[row * 64 + ((quad    ) ^ (row & 7)) * 8];
            vf[1][dt] = *(const short8*)&vbl[row * 64 + ((4 + quad) ^ (row & 7)) * 8];
        }
        // compacted mask (1 real / 0 pad) for this lane's keys
        float4 m4[4];
        #pragma unroll
        for (int nt = 0; nt < 4; ++nt)
            m4[nt] = *(const float4*)(mk + kbase + nt * 16 + quad * 4);

        #pragma unroll
        for (int g = 0; g < 2; ++g) {
            // S^T = K·Q^T : D[m=key][n=query]
            floatx4 st[4];
            #pragma unroll
            for (int nt = 0; nt < 4; ++nt) {
                floatx4 a = {0.f, 0.f, 0.f, 0.f};
                a = __builtin_amdgcn_mfma_f32_16x16x32_bf16(ka[nt][1], qa[g][1], a, 0, 0, 0);
                a = __builtin_amdgcn_mfma_f32_16x16x32_bf16(ka[nt][0], qa[g][0], a, 0, 0, 0);
                st[nt] = a;
            }
            // p = mask * exp2(s); P -> psh (swizzled, wave-private rows)
            const int prow = w * 32 + g * 16 + l15;
            float psum = 0.f;
            #pragma unroll
            for (int nt = 0; nt < 4; ++nt) {
                float p0 = m4[nt].x * __builtin_amdgcn_exp2f(st[nt][0]);
                float p1 = m4[nt].y * __builtin_amdgcn_exp2f(st[nt][1]);
                float p2 = m4[nt].z * __builtin_amdgcn_exp2f(st[nt][2]);
                float p3 = m4[nt].w * __builtin_amdgcn_exp2f(st[nt][3]);
                psum += (p0 + p1) + (p2 + p3);
                int2 pk = make_int2(f2bf_pk(p0, p1), f2bf_pk(p2, p3));
                const int c16 = (2 * nt + (quad >> 1)) ^ (prow & 7);
                *(int2*)&psh[prow * 64 + c16 * 8 + (quad & 1) * 4] = pk;
            }
            l_lane[g] += psum;
            // O^T += V^T·P^T (operand-swapped; same-wave psh write->read)
            #pragma unroll
            for (int kt = 0; kt < 2; ++kt) {
                short8 pa = *(const short8*)&psh[prow * 64 + ((kt * 4 + quad) ^ (prow & 7)) * 8];
                #pragma unroll
                for (int dt = 0; dt < 4; ++dt)
                    o_acc[g][dt] = __builtin_amdgcn_mfma_f32_16x16x32_bf16(vf[kt][dt], pa, o_acc[g][dt], 0, 0, 0);
            }
        }
        // no trailing barrier: next iteration writes the other buffer; the
        // single barrier per chunk orders writes@t+2 after all reads@t.
    }

    // epilogue: O^T layout => q=l15, d=dt*16+quad*4+i; float4 stores
    #pragma unroll
    for (int g = 0; g < 2; ++g) {
        float ls = l_lane[g];
        ls += __shfl_xor(ls, 16);
        ls += __shfl_xor(ls, 32);
        const float linv = 1.0f / ls;
        const int qr = qq * 128 + w * 32 + g * 16 + l15;
        float* orow = out + ((size_t)b * NQ_ + qr) * HD_ + h * D_;
        #pragma unroll
        for (int dt = 0; dt < 4; ++dt) {
            float4 v = make_float4(o_acc[g][dt][0] * linv, o_acc[g][dt][1] * linv,
                                   o_acc[g][dt][2] * linv, o_acc[g][dt][3] * linv);
            *(float4*)(orow + dt * 16 + quad * 4) = v;
        }
    }
}

extern "C" void kernel_launch(void* const* d_in, const int* in_sizes, int n_in,
                              void* d_out, int out_size, void* d_ws, size_t ws_size,
                              hipStream_t stream) {
    const float* query = (const float*)d_in[0];
    const float* key   = (const float*)d_in[1];
    const float* cmask = (const float*)d_in[2];
    const float* Wq    = (const float*)d_in[3];
    const float* bq    = (const float*)d_in[4];
    const float* Wk    = (const float*)d_in[5];
    const float* bk    = (const float*)d_in[6];
    const float* Wv    = (const float*)d_in[7];
    const float* bv    = (const float*)d_in[8];
    float* out = (float*)d_out;

    char* ws = (char*)d_ws;
    short* wqt = (short*)(ws);                           // 128 KB each
    short* wkt = (short*)(ws + 131072);
    short* wvt = (short*)(ws + 131072 * 2);
    float* bqs = (float*)(ws + 131072 * 3);              // 2 KB
    int*   idx = (int*)(ws + 131072 * 3 + 4096);         // 64 KB (16*1024 int)
    float* cm2 = (float*)(ws + 131072 * 3 + 4096 + 65536);   // 64 KB
    int*  npad = (int*)(ws + 131072 * 3 + 4096 + 131072);    // 64 B

    const float qscale = 0.125f * 1.44269504f;    // 1/sqrt(64) * log2(e)
    prep_kernel<<<dim3(65), dim3(256), 0, stream>>>(
        Wq, Wk, Wv, wqt, wkt, wvt, bq, bqs, qscale, cmask, idx, cm2, npad);

    fused_attn<<<dim3(512), dim3(256), 0, stream>>>(
        query, key, wqt, wkt, wvt, bk, bv, bqs, idx, cm2, npad, out);
}

// Round 7
// 135.312 us; speedup vs baseline: 1.6476x; 1.1610x over previous
//
#include <hip/hip_runtime.h>
#include <hip/hip_bf16.h>

#define B_  16
#define NQ_ 512
#define NK_ 1024
#define CQ_ 128
#define H_  8
#define D_  64
#define HD_ 512   // H*D

typedef __attribute__((ext_vector_type(8))) short short8;
typedef __attribute__((ext_vector_type(4))) float floatx4;

__device__ __forceinline__ short f2bf(float f) {
    union { float f; unsigned u; } x; x.f = f;
    unsigned r = (x.u + 0x7fffu + ((x.u >> 16) & 1u)) >> 16;  // RNE
    return (short)r;
}
__device__ __forceinline__ int f2bf_pk(float a, float b) {   // packed RNE (v_cvt_pk_bf16_f32)
    __hip_bfloat162 h = __float22bfloat162_rn(make_float2(a, b));
    int r; __builtin_memcpy(&r, &h, 4); return r;
}
__device__ __forceinline__ short8 pack8(float4 a, float4 b) {
    union { int4 i; short8 s; } u;
    u.i = make_int4(f2bf_pk(a.x, a.y), f2bf_pk(a.z, a.w),
                    f2bf_pk(b.x, b.y), f2bf_pk(b.z, b.w));
    return u.s;
}
__device__ __forceinline__ int2 packi2(floatx4 a) {
    return make_int2(f2bf_pk(a[0], a[1]), f2bf_pk(a[2], a[3]));
}
// async global->LDS, 16B per lane; LDS dest = uniform base + lane*16
__device__ __forceinline__ void async16(const short* g, short* l) {
    __builtin_amdgcn_global_load_lds(
        (const __attribute__((address_space(1))) void*)g,
        (__attribute__((address_space(3))) void*)l, 16, 0, 0);
}

// ---- Stage 0 (prep): W transposes + bqs + per-batch mask compaction ----
// blocks 0..47: LDS-tiled transpose W[128][512] -> Wt[512][128] bf16.
// block 48: bqs = bq*qscale.
// blocks 49..64: batch b=blk-49 mask compaction: idx[b][*] = unmasked key
// positions (order-preserving), cm2[b][*] = 1.0 (0.0 for pad), npad[b] =
// count rounded up to 128. Pad slots alias key row 0 (finite values, exact-0
// contribution via mask) so dropped keys change nothing.
__global__ __launch_bounds__(256) void prep_kernel(
    const float* __restrict__ W0, const float* __restrict__ W1,
    const float* __restrict__ W2, short* __restrict__ T0,
    short* __restrict__ T1, short* __restrict__ T2,
    const float* __restrict__ bq, float* __restrict__ bqs, float qscale,
    const float* __restrict__ cmask, int* __restrict__ idx,
    float* __restrict__ cm2, int* __restrict__ npad)
{
    const int blk = blockIdx.x, t = threadIdx.x;
    if (blk == 48) {
        bqs[t]       = bq[t] * qscale;
        bqs[t + 256] = bq[t + 256] * qscale;
        return;
    }
    if (blk >= 49) {   // ---- mask compaction for batch b ----
        __shared__ int wsum[4];
        const int b = blk - 49;
        const int w = t >> 6, lane = t & 63;
        float4 m4 = *(const float4*)(cmask + b * NK_ + t * 4);
        const int m0 = m4.x > 0.5f, m1 = m4.y > 0.5f, m2 = m4.z > 0.5f, m3 = m4.w > 0.5f;
        const int s = m0 + m1 + m2 + m3;
        int v = s;
        #pragma unroll
        for (int off = 1; off < 64; off <<= 1) {
            int u = __shfl_up(v, off);
            if (lane >= off) v += u;
        }
        if (lane == 63) wsum[w] = v;
        __syncthreads();
        int pre = 0;
        #pragma unroll
        for (int i = 0; i < 4; ++i) if (i < w) pre += wsum[i];
        int pos = pre + v - s;                 // exclusive prefix for this thread
        const int base = b * NK_;
        if (m0) { idx[base + pos] = t * 4 + 0; cm2[base + pos] = 1.0f; ++pos; }
        if (m1) { idx[base + pos] = t * 4 + 1; cm2[base + pos] = 1.0f; ++pos; }
        if (m2) { idx[base + pos] = t * 4 + 2; cm2[base + pos] = 1.0f; ++pos; }
        if (m3) { idx[base + pos] = t * 4 + 3; cm2[base + pos] = 1.0f; ++pos; }
        const int total = wsum[0] + wsum[1] + wsum[2] + wsum[3];
        for (int j = total + t; j < NK_; j += 256) {   // pad slots
            idx[base + j] = 0; cm2[base + j] = 0.0f;
        }
        if (t == 0) npad[b] = (total + 127) & ~127;
        return;
    }
    // ---- W transpose ----
    __shared__ short tsh[32 * 132];    // [n][k], pad 132
    const int mat = blk >> 4, nb = blk & 15;          // n0 = nb*32
    const float* W = mat == 0 ? W0 : (mat == 1 ? W1 : W2);
    short* T = mat == 0 ? T0 : (mat == 1 ? T1 : T2);
    const float s = mat == 0 ? qscale : 1.0f;
    #pragma unroll
    for (int i = 0; i < 4; ++i) {
        const int i2 = i * 256 + t;                   // 0..1023
        const int k = i2 >> 3, c = (i2 & 7) * 4;
        float4 v = *(const float4*)(W + (size_t)k * HD_ + nb * 32 + c);
        tsh[(c + 0) * 132 + k] = f2bf(v.x * s);
        tsh[(c + 1) * 132 + k] = f2bf(v.y * s);
        tsh[(c + 2) * 132 + k] = f2bf(v.z * s);
        tsh[(c + 3) * 132 + k] = f2bf(v.w * s);
    }
    __syncthreads();
    #pragma unroll
    for (int j = 0; j < 2; ++j) {
        const int i2 = j * 256 + t;                   // 0..511
        const int n = i2 >> 4, seg = (i2 & 15) * 8;
        *(short8*)(T + (size_t)(nb * 32 + n) * CQ_ + seg) =
            *(const short8*)&tsh[n * 132 + seg];
    }
}

// ---- Stage 1: K/V projection over COMPACTED keys, 4 heads per block ----
// grid.x: [0,128) k | [128,256) vT ; grid.y: head quad. Blocks whose 128-row
// tile lies beyond npad[b] exit immediately (block-uniform, pre-barrier).
__global__ __launch_bounds__(256, 2) void kvproj_kernel(
    const float* __restrict__ key_,
    const short* __restrict__ wkt, const short* __restrict__ wvt,
    const float* __restrict__ bk, const float* __restrict__ bv,
    short* __restrict__ ks, short* __restrict__ vt,
    const int* __restrict__ idx, const int* __restrict__ npad)
{
    __shared__ __align__(16) short csh[9216];   // k: [m][n] s72; v: [n][m] s136

    int bx = blockIdx.x;
    const short* Wt; const float* bias; short* out; int transposed;
    if (bx < 128) { Wt = wkt; bias = bk; out = ks; transposed = 0; }
    else { bx -= 128; Wt = wvt; bias = bv; out = vt; transposed = 1; }

    const int mbase = bx * 128;
    const int b  = mbase >> 10;
    const int r0 = mbase & 1023;
    if (r0 >= npad[b]) return;                  // compacted tail: nothing to do

    const int tid  = threadIdx.x;
    const int w    = tid >> 6, lane = tid & 63;
    const int l15  = lane & 15, quad = lane >> 4;
    const int* ib = idx + b * NK_;

    // A fragments gathered from fp32 key rows (rows 512B contiguous)
    short8 afr[2][4];
    #pragma unroll
    for (int mt = 0; mt < 2; ++mt) {
        const int krow = ib[r0 + w * 32 + mt * 16 + l15];
        const float* xrow = key_ + (size_t)(b * NK_ + krow) * CQ_;
        #pragma unroll
        for (int kt = 0; kt < 4; ++kt)
            afr[mt][kt] = pack8(*(const float4*)(xrow + kt * 32 + quad * 8),
                                *(const float4*)(xrow + kt * 32 + quad * 8 + 4));
    }

    #pragma unroll
    for (int hh = 0; hh < 4; ++hh) {
        const int h = blockIdx.y * 4 + hh;
        short8 bfr[4][4];
        #pragma unroll
        for (int nt = 0; nt < 4; ++nt) {
            const short8* wrow = (const short8*)(Wt + (size_t)(h * 64 + nt * 16 + l15) * CQ_);
            #pragma unroll
            for (int kt = 0; kt < 4; ++kt) bfr[nt][kt] = wrow[kt * 4 + quad];
        }
        floatx4 acc[2][4];
        #pragma unroll
        for (int mt = 0; mt < 2; ++mt)
            #pragma unroll
            for (int nt = 0; nt < 4; ++nt) {
                floatx4 a = {0.f, 0.f, 0.f, 0.f};
                #pragma unroll
                for (int kt = 0; kt < 4; ++kt)
                    a = __builtin_amdgcn_mfma_f32_16x16x32_bf16(afr[mt][kt], bfr[nt][kt], a, 0, 0, 0);
                acc[mt][nt] = a;
            }
        __syncthreads();   // previous head's csh reads done
        #pragma unroll
        for (int mt = 0; mt < 2; ++mt)
            #pragma unroll
            for (int nt = 0; nt < 4; ++nt) {
                const float bvv = bias[h * 64 + nt * 16 + l15];
                #pragma unroll
                for (int i = 0; i < 4; ++i) {
                    const short s = f2bf(acc[mt][nt][i] + bvv);
                    const int m = w * 32 + mt * 16 + quad * 4 + i;
                    const int n = nt * 16 + l15;
                    if (!transposed) csh[m * 72 + n]  = s;
                    else             csh[n * 136 + m] = s;
                }
            }
        __syncthreads();

        const size_t bh = (size_t)(b * H_ + h);
        if (!transposed) {
            short* dst = out + (bh * NK_ + r0) * D_;     // contiguous 8192-elem region
            #pragma unroll
            for (int it = 0; it < 4; ++it) {
                const int i2 = it * 256 + tid;           // 0..1023
                const int row = i2 >> 3, c8 = (i2 & 7) * 8;
                *(short8*)(dst + i2 * 8) = *(const short8*)&csh[row * 72 + c8];
            }
        } else {
            short* dst = out + bh * D_ * NK_ + r0;       // 64 rows x 128 cols, stride NK
            #pragma unroll
            for (int it = 0; it < 4; ++it) {
                const int i2 = it * 256 + tid;
                const int row = i2 >> 4, c8 = (i2 & 15) * 8;
                *(short8*)(dst + (size_t)row * NK_ + c8) = *(const short8*)&csh[row * 136 + c8];
            }
        }
    }
}

// ---- Stage 2: flash attention over compacted keys, fused Q-projection ----
// grid 512 = (qq bits7-8, bh bits0-6), 256 threads (4 waves, 32 q-rows each).
// Dynamic chunk count nc = npad[b]/64 (~8 instead of 16). qq-siblings of a
// (b,h) share bx%8 -> same XCD -> ks/vt slice reuse is L2-local already.
__global__ __launch_bounds__(256, 2) void attn_kernel(
    const float* __restrict__ query, const short* __restrict__ ks,
    const short* __restrict__ vt, const float* __restrict__ cm2,
    const short* __restrict__ wqt, const float* __restrict__ bqs,
    const int* __restrict__ npad, float* __restrict__ out)
{
    __shared__ __align__(16) short kbuf[2][64 * 64];
    __shared__ __align__(16) short vbuf[2][64 * 64];
    __shared__ __align__(16) short psh[128 * 64];    // swizzled, wave-private rows

    const int tid = threadIdx.x;
    const int w = tid >> 6, lane = tid & 63;
    const int l15 = lane & 15, quad = lane >> 4;

    const int bx   = blockIdx.x;
    const int bh_i = bx & 127;            // bh%8 tracks dispatch%8 -> XCD locality
    const int qq   = bx >> 7;             // 0..3 (128 q-rows each)
    const int h    = bh_i & 7;
    const int b    = bh_i >> 3;

    const size_t bh = (size_t)bh_i;
    const short* kb_ = ks + bh * NK_ * D_;
    const short* vb  = vt + bh * D_ * NK_;
    const float* mk  = cm2 + (size_t)b * NK_;
    const int nc = npad[b] >> 6;          // compacted chunk count

    // --- Phase A: Q projection (swapped: D[m=d][n=q]) via psh round-trip ---
    short8 qa[2][2];
    {
        short8 waf[4][4];
        #pragma unroll
        for (int dt = 0; dt < 4; ++dt)
            #pragma unroll
            for (int kt = 0; kt < 4; ++kt)
                waf[dt][kt] = *(const short8*)(wqt + (size_t)(h * 64 + dt * 16 + l15) * CQ_ + kt * 32 + quad * 8);
        const int qr0 = qq * 128 + w * 32;
        #pragma unroll
        for (int g = 0; g < 2; ++g) {
            const float* qrow = query + ((size_t)b * NQ_ + qr0 + g * 16 + l15) * CQ_;
            short8 bqf[4];
            #pragma unroll
            for (int kt = 0; kt < 4; ++kt)
                bqf[kt] = pack8(*(const float4*)(qrow + kt * 32 + quad * 8),
                                *(const float4*)(qrow + kt * 32 + quad * 8 + 4));
            const int prow = w * 32 + g * 16 + l15;
            #pragma unroll
            for (int dt = 0; dt < 4; ++dt) {
                float4 bi = *(const float4*)(bqs + h * 64 + dt * 16 + quad * 4);
                floatx4 a = {bi.x, bi.y, bi.z, bi.w};
                #pragma unroll
                for (int kt = 0; kt < 4; ++kt)
                    a = __builtin_amdgcn_mfma_f32_16x16x32_bf16(waf[dt][kt], bqf[kt], a, 0, 0, 0);
                const int c16 = (dt * 2 + (quad >> 1)) ^ (prow & 7);
                *(int2*)&psh[prow * 64 + c16 * 8 + (quad & 1) * 4] = packi2(a);
            }
            qa[g][0] = *(const short8*)&psh[prow * 64 + ((quad    ) ^ (prow & 7)) * 8];
            qa[g][1] = *(const short8*)&psh[prow * 64 + ((4 + quad) ^ (prow & 7)) * 8];
        }
    }

    // staging lane geometry: 8 lanes per row, 8 chunks of 16B per row
    const int srow8 = lane >> 3, sc = lane & 7;
    auto stage = [&](int kb0, short* kdst, short* vdst) {
        #pragma unroll
        for (int j = 0; j < 2; ++j) {
            const int row = w * 16 + j * 8 + srow8;
            const int cs = sc ^ (row & 7);
            async16(kb_ + (size_t)(kb0 + row) * D_ + cs * 8, &kdst[(w * 16 + j * 8) * 64]);
            async16(vb + (size_t)row * NK_ + kb0 + cs * 8, &vdst[(w * 16 + j * 8) * 64]);
        }
    };

    float l_lane[2] = {0.f, 0.f};
    floatx4 o_acc[2][4];
    #pragma unroll
    for (int g = 0; g < 2; ++g)
        #pragma unroll
        for (int dt = 0; dt < 4; ++dt) o_acc[g][dt] = (floatx4){0.f, 0.f, 0.f, 0.f};

    stage(0, kbuf[0], vbuf[0]);
    __syncthreads();

    for (int t = 0; t < nc; ++t) {
        const int cur = t & 1;
        if (t + 1 < nc) stage((t + 1) * 64, kbuf[cur ^ 1], vbuf[cur ^ 1]);
        const short* kb  = kbuf[cur];
        const short* vbl = vbuf[cur];
        const int kbase = t * 64;

        // K A-fragments (swizzled): A[m=key][k=d]
        short8 ka[4][2];
        #pragma unroll
        for (int nt = 0; nt < 4; ++nt) {
            const int row = nt * 16 + l15;
            ka[nt][0] = *(const short8*)&kb[row * 64 + ((quad    ) ^ (row & 7)) * 8];
            ka[nt][1] = *(const short8*)&kb[row * 64 + ((4 + quad) ^ (row & 7)) * 8];
        }
        // V fragments: lane map serves as A[m=d l15][k=key quad*8+j]
        short8 vf[2][4];
        #pragma unroll
        for (int dt = 0; dt < 4; ++dt) {
            const int row = dt * 16 + l15;
            vf[0][dt] = *(const short8*)&vbl[row * 64 + ((quad    ) ^ (row & 7)) * 8];
            vf[1][dt] = *(const short8*)&vbl[row * 64 + ((4 + quad) ^ (row & 7)) * 8];
        }
        // compacted mask (1 real / 0 pad) for this lane's keys
        float4 m4[4];
        #pragma unroll
        for (int nt = 0; nt < 4; ++nt)
            m4[nt] = *(const float4*)(mk + kbase + nt * 16 + quad * 4);

        #pragma unroll
        for (int g = 0; g < 2; ++g) {
            // S^T = K·Q^T : D[m=key][n=query]
            floatx4 st[4];
            #pragma unroll
            for (int nt = 0; nt < 4; ++nt) {
                floatx4 a = {0.f, 0.f, 0.f, 0.f};
                a = __builtin_amdgcn_mfma_f32_16x16x32_bf16(ka[nt][1], qa[g][1], a, 0, 0, 0);
                a = __builtin_amdgcn_mfma_f32_16x16x32_bf16(ka[nt][0], qa[g][0], a, 0, 0, 0);
                st[nt] = a;
            }
            // p = mask * exp2(s); P -> psh (swizzled, wave-private rows)
            const int prow = w * 32 + g * 16 + l15;
            float psum = 0.f;
            #pragma unroll
            for (int nt = 0; nt < 4; ++nt) {
                float p0 = m4[nt].x * __builtin_amdgcn_exp2f(st[nt][0]);
                float p1 = m4[nt].y * __builtin_amdgcn_exp2f(st[nt][1]);
                float p2 = m4[nt].z * __builtin_amdgcn_exp2f(st[nt][2]);
                float p3 = m4[nt].w * __builtin_amdgcn_exp2f(st[nt][3]);
                psum += (p0 + p1) + (p2 + p3);
                int2 pk = make_int2(f2bf_pk(p0, p1), f2bf_pk(p2, p3));
                const int c16 = (2 * nt + (quad >> 1)) ^ (prow & 7);
                *(int2*)&psh[prow * 64 + c16 * 8 + (quad & 1) * 4] = pk;
            }
            l_lane[g] += psum;
            // O^T += V^T·P^T (operand-swapped; same-wave psh write->read)
            #pragma unroll
            for (int kt = 0; kt < 2; ++kt) {
                short8 pa = *(const short8*)&psh[prow * 64 + ((kt * 4 + quad) ^ (prow & 7)) * 8];
                #pragma unroll
                for (int dt = 0; dt < 4; ++dt)
                    o_acc[g][dt] = __builtin_amdgcn_mfma_f32_16x16x32_bf16(vf[kt][dt], pa, o_acc[g][dt], 0, 0, 0);
            }
        }
        __syncthreads();   // next chunk staged + all waves done with this buffer
    }

    // epilogue: O^T layout => q=l15, d=dt*16+quad*4+i; float4 stores
    #pragma unroll
    for (int g = 0; g < 2; ++g) {
        float ls = l_lane[g];
        ls += __shfl_xor(ls, 16);
        ls += __shfl_xor(ls, 32);
        const float linv = 1.0f / ls;
        const int qr = qq * 128 + w * 32 + g * 16 + l15;
        float* orow = out + ((size_t)b * NQ_ + qr) * HD_ + h * D_;
        #pragma unroll
        for (int dt = 0; dt < 4; ++dt) {
            float4 v = make_float4(o_acc[g][dt][0] * linv, o_acc[g][dt][1] * linv,
                                   o_acc[g][dt][2] * linv, o_acc[g][dt][3] * linv);
            *(float4*)(orow + dt * 16 + quad * 4) = v;
        }
    }
}

extern "C" void kernel_launch(void* const* d_in, const int* in_sizes, int n_in,
                              void* d_out, int out_size, void* d_ws, size_t ws_size,
                              hipStream_t stream) {
    const float* query = (const float*)d_in[0];
    const float* key   = (const float*)d_in[1];
    const float* cmask = (const float*)d_in[2];
    const float* Wq    = (const float*)d_in[3];
    const float* bq    = (const float*)d_in[4];
    const float* Wk    = (const float*)d_in[5];
    const float* bk    = (const float*)d_in[6];
    const float* Wv    = (const float*)d_in[7];
    const float* bv    = (const float*)d_in[8];
    float* out = (float*)d_out;

    char* ws = (char*)d_ws;
    short* ks  = (short*)(ws);                           // 16 MB (B*H*NK*D bf16)
    short* vt  = (short*)(ws + (size_t)(16u << 20));     // 16 MB (B*H*D*NK bf16)
    char*  w32 = ws + (size_t)(32u << 20);
    short* wqt = (short*)(w32);                          // 128 KB each
    short* wkt = (short*)(w32 + 131072);
    short* wvt = (short*)(w32 + 131072 * 2);
    float* bqs = (float*)(w32 + 131072 * 3);             // 2 KB
    int*   idx = (int*)(w32 + 131072 * 3 + 4096);        // 64 KB (16*1024 int)
    float* cm2 = (float*)(w32 + 131072 * 3 + 4096 + 65536);  // 64 KB
    int*  npad = (int*)(w32 + 131072 * 3 + 4096 + 131072);   // 64 B

    const float qscale = 0.125f * 1.44269504f;    // 1/sqrt(64) * log2(e)
    prep_kernel<<<dim3(65), dim3(256), 0, stream>>>(
        Wq, Wk, Wv, wqt, wkt, wvt, bq, bqs, qscale, cmask, idx, cm2, npad);

    kvproj_kernel<<<dim3(256, 2), dim3(256), 0, stream>>>(
        key, wkt, wvt, bk, bv, ks, vt, idx, npad);

    attn_kernel<<<dim3(512), dim3(256), 0, stream>>>(
        query, ks, vt, cm2, wqt, bqs, npad, out);
}